// Round 6
// baseline (246.137 us; speedup 1.0000x reference)
//
#include <hip/hip_runtime.h>

#define N_EDGE 40000

typedef float f32x2 __attribute__((ext_vector_type(2)));

// ===================== compile-time CG machinery =============================
constexpr double csqrt(double x) {
    if (x <= 0.0) return 0.0;
    double g = x < 1.0 ? 1.0 : x;
    for (int i = 0; i < 40; ++i) g = 0.5 * (g + x / g);
    return g;
}
constexpr double dfact(int n) {
    double r = 1.0;
    for (int i = 2; i <= n; ++i) r *= (double)i;
    return r;
}
constexpr int cmax(int a, int b) { return a > b ? a : b; }
constexpr int cmin(int a, int b) { return a < b ? a : b; }

constexpr double cg_coeff(int j1, int m1, int j2, int m2, int j3, int m3) {
    if (m3 != m1 + m2) return 0.0;
    int vmin = cmax(0, cmax(j2 - j3 - m1, j1 - j3 + m2));
    int vmax = cmin(j1 + j2 - j3, cmin(j1 - m1, j2 + m2));
    if (vmax < vmin) return 0.0;
    double pref = csqrt((double)(2 * j3 + 1) * dfact(j3 + j1 - j2) * dfact(j3 - j1 + j2) *
                        dfact(j1 + j2 - j3) / dfact(j1 + j2 + j3 + 1));
    pref *= csqrt(dfact(j3 + m3) * dfact(j3 - m3) * dfact(j1 - m1) * dfact(j1 + m1) *
                  dfact(j2 - m2) * dfact(j2 + m2));
    double s = 0.0;
    for (int v = vmin; v <= vmax; ++v) {
        double term = 1.0 / (dfact(v) * dfact(j1 + j2 - j3 - v) * dfact(j1 - m1 - v) *
                             dfact(j2 + m2 - v) * dfact(j3 - j2 + m1 + v) * dfact(j3 - j1 - m2 + v));
        s += (v & 1) ? -term : term;
    }
    return pref * s;
}

constexpr void make_q(int l, double* qre, double* qim) {
    int n = 2 * l + 1;
    for (int i = 0; i < n * n; ++i) { qre[i] = 0.0; qim[i] = 0.0; }
    const double s = 0.70710678118654752440;
    for (int m = -l; m < 0; ++m) {
        int am = -m;
        qre[(l + m) * n + (l + am)] = s;
        qim[(l + m) * n + (l - am)] = -s;
    }
    qre[l * n + l] = 1.0;
    for (int m = 1; m <= l; ++m) {
        double sgn = (m & 1) ? -1.0 : 1.0;
        qre[(l + m) * n + (l + m)] = sgn * s;
        qim[(l + m) * n + (l - m)] = sgn * s;
    }
    int ph = l & 3;
    if (ph) {
        for (int i = 0; i < n * n; ++i) {
            double re = qre[i], im = qim[i];
            if (ph == 1)      { qre[i] =  im; qim[i] = -re; }
            else if (ph == 2) { qre[i] = -re; qim[i] = -im; }
            else              { qre[i] = -im; qim[i] =  re; }
        }
    }
}

template <int L1, int L2, int L3>
struct RealCG {
    static constexpr int N1 = 2 * L1 + 1, N2 = 2 * L2 + 1, N3 = 2 * L3 + 1;
    float v[N1 * N2 * N3];
    constexpr RealCG() : v{} {
        double cg[N1 * N2 * N3] = {};
        for (int i = 0; i < N1; ++i)
            for (int j = 0; j < N2; ++j) {
                int m1 = i - L1, m2 = j - L2, m3 = m1 + m2;
                if (m3 >= -L3 && m3 <= L3)
                    cg[(i * N2 + j) * N3 + (m3 + L3)] = cg_coeff(L1, m1, L2, m2, L3, m3);
            }
        double q1r[N1 * N1] = {}, q1i[N1 * N1] = {};
        double q2r[N2 * N2] = {}, q2i[N2 * N2] = {};
        double q3r[N3 * N3] = {}, q3i[N3 * N3] = {};
        make_q(L1, q1r, q1i);
        make_q(L2, q2r, q2i);
        make_q(L3, q3r, q3i);
        double dr[N1 * N2 * N3] = {}, di[N1 * N2 * N3] = {};
        for (int i = 0; i < N1; ++i)
            for (int j = 0; j < N2; ++j)
                for (int k = 0; k < N3; ++k) {
                    double accr = 0.0, acci = 0.0;
                    for (int a = 0; a < N1; ++a) {
                        double x1r = q1r[i * N1 + a], x1i = q1i[i * N1 + a];
                        if (x1r == 0.0 && x1i == 0.0) continue;
                        for (int b = 0; b < N2; ++b) {
                            double x2r = q2r[j * N2 + b], x2i = q2i[j * N2 + b];
                            if (x2r == 0.0 && x2i == 0.0) continue;
                            double wr = x1r * x2r - x1i * x2i;
                            double wi = x1r * x2i + x1i * x2r;
                            for (int cc = 0; cc < N3; ++cc) {
                                double g = cg[(a * N2 + b) * N3 + cc];
                                if (g == 0.0) continue;
                                double zr = q3r[k * N3 + cc];
                                double zi = -q3i[k * N3 + cc];  // conj
                                accr += (wr * zr - wi * zi) * g;
                                acci += (wr * zi + wi * zr) * g;
                            }
                        }
                    }
                    dr[(i * N2 + j) * N3 + k] = accr;
                    di[(i * N2 + j) * N3 + k] = acci;
                }
        double sr = 0.0, si = 0.0;
        for (int t = 0; t < N1 * N2 * N3; ++t) { sr += dr[t] * dr[t]; si += di[t] * di[t]; }
        bool use_re = (sr >= si);
        double nrm = csqrt(use_re ? sr : si);
        for (int t = 0; t < N1 * N2 * N3; ++t) {
            double val = (use_re ? dr[t] : di[t]) / nrm;
            if (val < 1e-7 && val > -1e-7) val = 0.0;  // drop cancellation residue
            v[t] = (float)val;
        }
    }
};

template <int L1, int L2, int L3>
inline constexpr RealCG<L1, L2, L3> g_rcg{};

// ===================== compile-time unroller =================================
template <int I> struct ic { static constexpr int value = I; };

template <int N, int I = 0, class F>
__device__ __forceinline__ void cunroll(F&& f) {
    if constexpr (I < N) {
        f(ic<I>{});
        cunroll<N, I + 1>(f);
    }
}

// ===================== main tensor-product kernel ============================
// CG values are compile-time float literals (exact zeros pruned). Each lane
// owns a CHANNEL PAIR of one edge: all x loads and out stores are 8 B/lane
// (512 B per wave instruction). Stores nontemporal (out never re-read);
// x loads nontemporal (pure stream, each element read by exactly one lane).
template <int L1, int L2, int L3, int RO>
__device__ __forceinline__ void do_path(const f32x2* xv, const float* yv, float* o) {
    constexpr int N2 = 2 * L2 + 1, N3 = 2 * L3 + 1;
    constexpr int X0 = L1 * L1, Y0 = L2 * L2;
    f32x2 a[N3];
    cunroll<N3>([&](auto K) { a[K.value] = (f32x2)(0.f); });
    cunroll<2 * L1 + 1>([&](auto I) {
        cunroll<N2>([&](auto J) {
            const float yj = yv[Y0 + J.value];
            const float t0 = xv[X0 + I.value].x * yj;
            const float t1 = xv[X0 + I.value].y * yj;
            cunroll<N3>([&](auto K) {
                constexpr float cgv =
                    g_rcg<L1, L2, L3>.v[(I.value * N2 + J.value) * N3 + K.value];
                if constexpr (cgv != 0.0f) {
                    a[K.value].x += cgv * t0;
                    a[K.value].y += cgv * t1;
                }
            });
        });
    });
    cunroll<N3>([&](auto K) {
        __builtin_nontemporal_store(a[K.value], (f32x2*)(o + (RO + K.value) * 64));
    });
}

__global__ __launch_bounds__(256) void tp_main_kernel(const float* __restrict__ x,
                                                      const float* __restrict__ y,
                                                      float* __restrict__ out) {
    const int lane = threadIdx.x & 63;
    const int wv   = threadIdx.x >> 6;
    const int half = lane >> 5;          // which of the wave's 2 edges
    const int cl   = lane & 31;          // channel-pair index: channels 2cl, 2cl+1
    const int e    = blockIdx.x * 8 + wv * 2 + half;

    const float* xp = x + (size_t)e * 1024 + cl * 2;
    f32x2 xv[16];
#pragma unroll
    for (int i = 0; i < 16; ++i)
        xv[i] = __builtin_nontemporal_load((const f32x2*)(xp + i * 64));

    const float* yp = y + (size_t)e * 16;
    float yv[16];
#pragma unroll
    for (int j = 0; j < 16; ++j) yv[j] = yp[j];

    float* o = out + (size_t)e * 99 * 64 + cl * 2;

    do_path<0,0,0,  0>(xv, yv, o);
    do_path<0,1,1,  1>(xv, yv, o);
    do_path<0,2,2,  4>(xv, yv, o);
    do_path<0,3,3,  9>(xv, yv, o);
    do_path<1,0,1, 16>(xv, yv, o);
    do_path<1,1,0, 19>(xv, yv, o);
    do_path<1,1,2, 20>(xv, yv, o);
    do_path<1,2,1, 25>(xv, yv, o);
    do_path<1,2,3, 28>(xv, yv, o);
    do_path<1,3,2, 35>(xv, yv, o);
    do_path<2,0,2, 40>(xv, yv, o);
    do_path<2,1,1, 45>(xv, yv, o);
    do_path<2,1,3, 48>(xv, yv, o);
    do_path<2,2,0, 55>(xv, yv, o);
    do_path<2,2,2, 56>(xv, yv, o);
    do_path<2,3,1, 61>(xv, yv, o);
    do_path<2,3,3, 64>(xv, yv, o);
    do_path<3,0,3, 71>(xv, yv, o);
    do_path<3,1,2, 78>(xv, yv, o);
    do_path<3,2,1, 83>(xv, yv, o);
    do_path<3,2,3, 86>(xv, yv, o);
    do_path<3,3,0, 93>(xv, yv, o);
    do_path<3,3,2, 94>(xv, yv, o);
}

// ===================== launch ================================================
extern "C" void kernel_launch(void* const* d_in, const int* in_sizes, int n_in,
                              void* d_out, int out_size, void* d_ws, size_t ws_size,
                              hipStream_t stream) {
    const float* x = (const float*)d_in[0];
    const float* y = (const float*)d_in[1];
    float* out = (float*)d_out;

    // 5000 blocks x 4 waves x 2 edges = 40000 edges; single launch, no LDS,
    // CG baked as instruction-stream literals, float2 memory ops throughout.
    tp_main_kernel<<<dim3(N_EDGE / 8), dim3(256), 0, stream>>>(x, y, out);
}

// Round 7
// 197.657 us; speedup vs baseline: 1.2453x; 1.2453x over previous
//
#include <hip/hip_runtime.h>

#define N_EDGE 40000

// ===================== compile-time CG machinery =============================
constexpr double csqrt(double x) {
    if (x <= 0.0) return 0.0;
    double g = x < 1.0 ? 1.0 : x;
    for (int i = 0; i < 40; ++i) g = 0.5 * (g + x / g);
    return g;
}
constexpr double dfact(int n) {
    double r = 1.0;
    for (int i = 2; i <= n; ++i) r *= (double)i;
    return r;
}
constexpr int cmax(int a, int b) { return a > b ? a : b; }
constexpr int cmin(int a, int b) { return a < b ? a : b; }

constexpr double cg_coeff(int j1, int m1, int j2, int m2, int j3, int m3) {
    if (m3 != m1 + m2) return 0.0;
    int vmin = cmax(0, cmax(j2 - j3 - m1, j1 - j3 + m2));
    int vmax = cmin(j1 + j2 - j3, cmin(j1 - m1, j2 + m2));
    if (vmax < vmin) return 0.0;
    double pref = csqrt((double)(2 * j3 + 1) * dfact(j3 + j1 - j2) * dfact(j3 - j1 + j2) *
                        dfact(j1 + j2 - j3) / dfact(j1 + j2 + j3 + 1));
    pref *= csqrt(dfact(j3 + m3) * dfact(j3 - m3) * dfact(j1 - m1) * dfact(j1 + m1) *
                  dfact(j2 - m2) * dfact(j2 + m2));
    double s = 0.0;
    for (int v = vmin; v <= vmax; ++v) {
        double term = 1.0 / (dfact(v) * dfact(j1 + j2 - j3 - v) * dfact(j1 - m1 - v) *
                             dfact(j2 + m2 - v) * dfact(j3 - j2 + m1 + v) * dfact(j3 - j1 - m2 + v));
        s += (v & 1) ? -term : term;
    }
    return pref * s;
}

constexpr void make_q(int l, double* qre, double* qim) {
    int n = 2 * l + 1;
    for (int i = 0; i < n * n; ++i) { qre[i] = 0.0; qim[i] = 0.0; }
    const double s = 0.70710678118654752440;
    for (int m = -l; m < 0; ++m) {
        int am = -m;
        qre[(l + m) * n + (l + am)] = s;
        qim[(l + m) * n + (l - am)] = -s;
    }
    qre[l * n + l] = 1.0;
    for (int m = 1; m <= l; ++m) {
        double sgn = (m & 1) ? -1.0 : 1.0;
        qre[(l + m) * n + (l + m)] = sgn * s;
        qim[(l + m) * n + (l - m)] = sgn * s;
    }
    int ph = l & 3;
    if (ph) {
        for (int i = 0; i < n * n; ++i) {
            double re = qre[i], im = qim[i];
            if (ph == 1)      { qre[i] =  im; qim[i] = -re; }
            else if (ph == 2) { qre[i] = -re; qim[i] = -im; }
            else              { qre[i] = -im; qim[i] =  re; }
        }
    }
}

template <int L1, int L2, int L3>
struct RealCG {
    static constexpr int N1 = 2 * L1 + 1, N2 = 2 * L2 + 1, N3 = 2 * L3 + 1;
    float v[N1 * N2 * N3];
    constexpr RealCG() : v{} {
        double cg[N1 * N2 * N3] = {};
        for (int i = 0; i < N1; ++i)
            for (int j = 0; j < N2; ++j) {
                int m1 = i - L1, m2 = j - L2, m3 = m1 + m2;
                if (m3 >= -L3 && m3 <= L3)
                    cg[(i * N2 + j) * N3 + (m3 + L3)] = cg_coeff(L1, m1, L2, m2, L3, m3);
            }
        double q1r[N1 * N1] = {}, q1i[N1 * N1] = {};
        double q2r[N2 * N2] = {}, q2i[N2 * N2] = {};
        double q3r[N3 * N3] = {}, q3i[N3 * N3] = {};
        make_q(L1, q1r, q1i);
        make_q(L2, q2r, q2i);
        make_q(L3, q3r, q3i);
        double dr[N1 * N2 * N3] = {}, di[N1 * N2 * N3] = {};
        for (int i = 0; i < N1; ++i)
            for (int j = 0; j < N2; ++j)
                for (int k = 0; k < N3; ++k) {
                    double accr = 0.0, acci = 0.0;
                    for (int a = 0; a < N1; ++a) {
                        double x1r = q1r[i * N1 + a], x1i = q1i[i * N1 + a];
                        if (x1r == 0.0 && x1i == 0.0) continue;
                        for (int b = 0; b < N2; ++b) {
                            double x2r = q2r[j * N2 + b], x2i = q2i[j * N2 + b];
                            if (x2r == 0.0 && x2i == 0.0) continue;
                            double wr = x1r * x2r - x1i * x2i;
                            double wi = x1r * x2i + x1i * x2r;
                            for (int cc = 0; cc < N3; ++cc) {
                                double g = cg[(a * N2 + b) * N3 + cc];
                                if (g == 0.0) continue;
                                double zr = q3r[k * N3 + cc];
                                double zi = -q3i[k * N3 + cc];  // conj
                                accr += (wr * zr - wi * zi) * g;
                                acci += (wr * zi + wi * zr) * g;
                            }
                        }
                    }
                    dr[(i * N2 + j) * N3 + k] = accr;
                    di[(i * N2 + j) * N3 + k] = acci;
                }
        double sr = 0.0, si = 0.0;
        for (int t = 0; t < N1 * N2 * N3; ++t) { sr += dr[t] * dr[t]; si += di[t] * di[t]; }
        bool use_re = (sr >= si);
        double nrm = csqrt(use_re ? sr : si);
        for (int t = 0; t < N1 * N2 * N3; ++t) {
            double val = (use_re ? dr[t] : di[t]) / nrm;
            if (val < 1e-7 && val > -1e-7) val = 0.0;  // drop cancellation residue
            v[t] = (float)val;
        }
    }
};

template <int L1, int L2, int L3>
inline constexpr RealCG<L1, L2, L3> g_rcg{};

// ===================== compile-time unroller =================================
template <int I> struct ic { static constexpr int value = I; };

template <int N, int I = 0, class F>
__device__ __forceinline__ void cunroll(F&& f) {
    if constexpr (I < N) {
        f(ic<I>{});
        cunroll<N, I + 1>(f);
    }
}

// ===================== main tensor-product kernel ============================
// R5 configuration (best measured: 196.5 us).
// - CG values are compile-time float literals; exact zeros pruned by
//   `if constexpr` (no LDS, no setup kernel, single launch).
// - 1 edge per wave, lane = channel: every x load and out store is one
//   contiguous 256 B segment per wave-instruction (R6 showed that splitting
//   a wave across 2 edges -> 2 segments/instr regresses 25%).
// - Output stores NONTEMPORAL (1.01 GB, never re-read; keep L2 clean).
// - x loads regular (cached); nt loads regressed in R6.
template <int L1, int L2, int L3, int RO>
__device__ __forceinline__ void do_path(const float* xv, const float* yv, float* o) {
    constexpr int N2 = 2 * L2 + 1, N3 = 2 * L3 + 1;
    constexpr int X0 = L1 * L1, Y0 = L2 * L2;
    float a[N3];
    cunroll<N3>([&](auto K) { a[K.value] = 0.f; });
    cunroll<2 * L1 + 1>([&](auto I) {
        cunroll<N2>([&](auto J) {
            float t = xv[X0 + I.value] * yv[Y0 + J.value];  // DCE'd if all k pruned
            cunroll<N3>([&](auto K) {
                constexpr float cgv =
                    g_rcg<L1, L2, L3>.v[(I.value * N2 + J.value) * N3 + K.value];
                if constexpr (cgv != 0.0f) a[K.value] += cgv * t;
            });
        });
    });
    cunroll<N3>([&](auto K) {
        __builtin_nontemporal_store(a[K.value], o + (RO + K.value) * 64);
    });
}

__global__ __launch_bounds__(256) void tp_main_kernel(const float* __restrict__ x,
                                                      const float* __restrict__ y,
                                                      float* __restrict__ out) {
    const int c = threadIdx.x & 63;
    const int e = blockIdx.x * 4 + (threadIdx.x >> 6);  // 1 edge per wave

    const float* xp = x + (size_t)e * 1024 + c;
    float xv[16];
#pragma unroll
    for (int i = 0; i < 16; ++i) xv[i] = xp[i * 64];   // regular loads

    const float* yp = y + (size_t)e * 16;
    float yv[16];
#pragma unroll
    for (int j = 0; j < 16; ++j) yv[j] = yp[j];

    float* o = out + (size_t)e * 99 * 64 + c;

    do_path<0,0,0,  0>(xv, yv, o);
    do_path<0,1,1,  1>(xv, yv, o);
    do_path<0,2,2,  4>(xv, yv, o);
    do_path<0,3,3,  9>(xv, yv, o);
    do_path<1,0,1, 16>(xv, yv, o);
    do_path<1,1,0, 19>(xv, yv, o);
    do_path<1,1,2, 20>(xv, yv, o);
    do_path<1,2,1, 25>(xv, yv, o);
    do_path<1,2,3, 28>(xv, yv, o);
    do_path<1,3,2, 35>(xv, yv, o);
    do_path<2,0,2, 40>(xv, yv, o);
    do_path<2,1,1, 45>(xv, yv, o);
    do_path<2,1,3, 48>(xv, yv, o);
    do_path<2,2,0, 55>(xv, yv, o);
    do_path<2,2,2, 56>(xv, yv, o);
    do_path<2,3,1, 61>(xv, yv, o);
    do_path<2,3,3, 64>(xv, yv, o);
    do_path<3,0,3, 71>(xv, yv, o);
    do_path<3,1,2, 78>(xv, yv, o);
    do_path<3,2,1, 83>(xv, yv, o);
    do_path<3,2,3, 86>(xv, yv, o);
    do_path<3,3,0, 93>(xv, yv, o);
    do_path<3,3,2, 94>(xv, yv, o);
}

// ===================== launch ================================================
extern "C" void kernel_launch(void* const* d_in, const int* in_sizes, int n_in,
                              void* d_out, int out_size, void* d_ws, size_t ws_size,
                              hipStream_t stream) {
    const float* x = (const float*)d_in[0];
    const float* y = (const float*)d_in[1];
    float* out = (float*)d_out;

    // 10000 blocks x 4 waves x 1 edge = 40000 edges; single launch, no LDS,
    // CG baked as instruction-stream literals at compile time.
    tp_main_kernel<<<dim3(N_EDGE / 4), dim3(256), 0, stream>>>(x, y, out);
}